// Round 7
// baseline (308.029 us; speedup 1.0000x reference)
//
#include <hip/hip_runtime.h>
#include <stdint.h>

#define NPRED 2048
#define MT    512
#define BLK   256
#define NCAND 512
#define REC   2176   // per-batch ws: srt[512]u16 | (unused 1024B) | meta[8]i32

#define M_NPOS  0
#define M_NT    1
#define M_K     2

template<int C>
__device__ __forceinline__ float dppminf(float v) {
  int o = __builtin_amdgcn_update_dpp(__float_as_int(v), __float_as_int(v), C, 0xF, 0xF, false);
  return fminf(v, __int_as_float(o));
}
template<int C>
__device__ __forceinline__ uint32_t dppminu(uint32_t v) {
  uint32_t o = (uint32_t)__builtin_amdgcn_update_dpp((int)v, (int)v, C, 0xF, 0xF, false);
  return v < o ? v : o;
}
__device__ __forceinline__ float wave_min_f32_l63(float v) {
  v = dppminf<0x111>(v); v = dppminf<0x112>(v); v = dppminf<0x114>(v);
  v = dppminf<0x118>(v); v = dppminf<0x142>(v); v = dppminf<0x143>(v);
  return __int_as_float(__builtin_amdgcn_readlane(__float_as_int(v), 63));
}
__device__ __forceinline__ uint32_t wave_min_u32_l63(uint32_t v) {
  v = dppminu<0x111>(v); v = dppminu<0x112>(v); v = dppminu<0x114>(v);
  v = dppminu<0x118>(v); v = dppminu<0x142>(v); v = dppminu<0x143>(v);
  return (uint32_t)__builtin_amdgcn_readlane((int)v, 63);
}

// select lep entry j (runtime j) from 8 packed u32 (16 x u16) via cndmask tree
__device__ __forceinline__ uint32_t sel16le(const uint32_t lep[8], uint32_t j) {
  uint32_t a0 = (j & 2) ? lep[1] : lep[0];
  uint32_t a1 = (j & 2) ? lep[3] : lep[2];
  uint32_t a2 = (j & 2) ? lep[5] : lep[4];
  uint32_t a3 = (j & 2) ? lep[7] : lep[6];
  uint32_t b0 = (j & 4) ? a1 : a0;
  uint32_t b1 = (j & 4) ? a3 : a2;
  uint32_t r = (j & 8) ? b1 : b0;
  return (j & 1) ? (r >> 16) : (r & 0xFFFFu);
}

// ---- bitonic helpers (static indexing; u32 keys) ----
__device__ __forceinline__ void ce_asc(uint32_t& a, uint32_t& b) {
  uint32_t lo = a < b ? a : b;
  uint32_t hi = a < b ? b : a;
  a = lo; b = hi;
}
__device__ __forceinline__ void ce_desc(uint32_t& a, uint32_t& b) {
  uint32_t lo = a < b ? a : b;
  uint32_t hi = a < b ? b : a;
  a = hi; b = lo;
}
__device__ __forceinline__ void bsort16(uint32_t k[16]) {
#pragma unroll
  for (int kk = 2; kk <= 16; kk <<= 1) {
#pragma unroll
    for (int j = kk >> 1; j > 0; j >>= 1) {
#pragma unroll
      for (int i = 0; i < 16; ++i) {
        int p = i ^ j;
        if (p > i) {
          if ((i & kk) == 0) ce_asc(k[i], k[p]); else ce_desc(k[i], k[p]);
        }
      }
    }
  }
}
__device__ __forceinline__ void bclean16(uint32_t k[16]) {
#pragma unroll
  for (int j = 8; j > 0; j >>= 1) {
#pragma unroll
    for (int i = 0; i < 16; ++i) {
      int p = i ^ j;
      if (p > i) ce_asc(k[i], k[p]);
    }
  }
}

// ---------------- K1: select + rank-sort + prob loss ----------------
__global__ __launch_bounds__(BLK) void prep_kernel(const float* __restrict__ preds,
                                                   const float* __restrict__ targets,
                                                   uint8_t* __restrict__ recs,
                                                   double* __restrict__ acc) {
  const int b = blockIdx.x;
  const float* __restrict__ P = preds   + (size_t)b * NPRED * 5;
  const float* __restrict__ T = targets + (size_t)b * MT * 5;
  uint16_t* __restrict__ srt = (uint16_t*)(recs + (size_t)b * REC);
  int* __restrict__ meta = (int*)(recs + (size_t)b * REC + 2048);

  __shared__ uint64_t keys[NPRED];
  __shared__ uint64_t cand[NCAND];
  __shared__ int hist[256];
  __shared__ int s_npos, s_nt, s_B, s_ncand;
  __shared__ uint64_t s_thr;
  __shared__ double red[BLK];

  const int tid = threadIdx.x;
  if (tid == 0) { s_npos = 0; s_nt = 0; s_B = 0; s_ncand = 0; s_thr = 0ull; }
  hist[tid] = 0;
  __syncthreads();

  int cpos = 0;
  for (int i = tid; i < NPRED; i += BLK) {
    float c = P[i * 5 + 0];
    cpos += (c > 0.5f) ? 1 : 0;
    uint32_t cb = __float_as_uint(c);
    keys[i] = ((uint64_t)(~cb) << 32) | (uint32_t)i;
    if (cb >= 0x3F000000u && cb < 0x3F800000u)
      atomicAdd(&hist[(cb >> 15) & 0xFF], 1);
  }
  atomicAdd(&s_npos, cpos);

  int ct = 0;
  for (int m = tid; m < MT; m += BLK) ct += (T[m * 5 + 0] == 1.0f) ? 1 : 0;
  atomicAdd(&s_nt, ct);
  __syncthreads();
  const int n_pos = s_npos;
  const int n_targs = s_nt;

  if (tid < 64) {
    const int lane = tid;
    int4 h4 = *reinterpret_cast<const int4*>(&hist[lane * 4]);
    int t = h4.x + h4.y + h4.z + h4.w;
    int S = t;
#pragma unroll
    for (int off = 1; off < 64; off <<= 1) {
      int o = __shfl_down(S, off);
      if (lane + off < 64) S += o;
    }
    int Snext = S - t;
    int s3 = h4.w + Snext;
    int s2 = h4.z + s3;
    int s1 = h4.y + s2;
    int s0 = h4.x + s1;
    int localB = -1;
    if      (s3 >= n_targs) localB = lane * 4 + 3;
    else if (s2 >= n_targs) localB = lane * 4 + 2;
    else if (s1 >= n_targs) localB = lane * 4 + 1;
    else if (s0 >= n_targs) localB = lane * 4 + 0;
    uint64_t q = __ballot(localB >= 0);
    if (q) {
      int hl = 63 - __clzll((long long)q);
      int B = __builtin_amdgcn_readlane(localB, hl);
      if (lane == 0) s_B = B;
    }
  }
  for (int i = tid; i < NCAND; i += BLK) srt[i] = 0;
  __syncthreads();
  const int B = s_B;

  for (int i = tid; i < NPRED; i += BLK) {
    uint64_t k = keys[i];
    uint32_t cb = ~(uint32_t)(k >> 32);
    if (cb >= 0x3F000000u && cb < 0x3F800000u && (int)((cb >> 15) & 0xFF) >= B) {
      int slot = atomicAdd(&s_ncand, 1);
      if (slot < NCAND) cand[slot] = k;
    }
  }
  __syncthreads();
  const int ncand = min(s_ncand, NCAND);

  {
    uint64_t ka = (tid < ncand) ? cand[tid] : ~0ull;
    uint64_t kb = (tid + BLK < ncand) ? cand[tid + BLK] : ~0ull;
    int ra = 0, rb = 0;
    for (int j = 0; j < ncand; ++j) {
      uint64_t kj = cand[j];
      ra += (kj < ka) ? 1 : 0;
      rb += (kj < kb) ? 1 : 0;
    }
    if (tid < ncand) {
      srt[ra] = (uint16_t)(ka & 0xFFFFu);
      if (ra == n_targs - 1) s_thr = ka;
    }
    if (tid + BLK < ncand) {
      srt[rb] = (uint16_t)(kb & 0xFFFFu);
      if (rb == n_targs - 1) s_thr = kb;
    }
  }
  __syncthreads();
  const uint64_t thr = s_thr;

  float accp = 0.f;
  for (int i = tid; i < NPRED; i += BLK) {
    uint64_t k = keys[i];
    float p = __uint_as_float(~(uint32_t)(k >> 32));
    accp += (k <= thr) ? -fmaxf(logf(p), -100.0f)
                       : -fmaxf(log1pf(-p), -100.0f);
  }
  red[tid] = (double)accp;
  __syncthreads();
  for (int s = BLK / 2; s > 0; s >>= 1) {
    if (tid < s) red[tid] += red[tid + s];
    __syncthreads();
  }
  if (tid == 0) {
    atomicAdd(&acc[4], red[0]);
    meta[M_NPOS] = n_pos;
    meta[M_NT]   = n_targs;
    meta[M_K]    = min(n_pos, n_targs);
  }
}

// ---------------- K2: lists + parallel-fixpoint greedy + MSE ----------------
__global__ __launch_bounds__(BLK) void match_mse_kernel(const float* __restrict__ preds,
                                                        const float* __restrict__ targets,
                                                        const uint8_t* __restrict__ recs,
                                                        double* __restrict__ acc) {
  const int b = blockIdx.x;
  const int tid = threadIdx.x;
  const float* __restrict__ P = preds   + (size_t)b * NPRED * 5;
  const float* __restrict__ T = targets + (size_t)b * MT * 5;
  const uint16_t* __restrict__ srt = (const uint16_t*)(recs + (size_t)b * REC);
  const int* __restrict__ meta = (const int*)(recs + (size_t)b * REC + 2048);

  __shared__ float txy[MT * 2];                        // 4 KB
  __shared__ float tab[MT * 2];                        // 4 KB
  __shared__ float spx[512], spy[512], spa[512], spb[512]; // 8 KB
  __shared__ __align__(16) uint16_t lists[512 * 16];   // 16 KB
  __shared__ uint16_t picks[512];                      // 1 KB
  __shared__ uint32_t owner[512];                      // 2 KB
  __shared__ uint32_t validw[16], avail[16], s_res[16];
  __shared__ uint64_t wavemin[4];
  __shared__ int s_changed, s_event, s_first;
  __shared__ double red[4][BLK];                       // 8 KB

  const int n_pos = meta[M_NPOS], n_targs = meta[M_NT], K = meta[M_K];

  if (tid < 16) { validw[tid] = 0; s_res[tid] = 0; }
  if (tid == 0) s_first = 0;
  __syncthreads();

  // ---- stage targets (poison invalid x); validity bits ----
  for (int m = tid; m < MT; m += BLK) {
    float tp = T[m * 5 + 0];
    bool v = (tp == 1.0f);
    txy[2 * m]     = v ? T[m * 5 + 1] : 1e18f;
    txy[2 * m + 1] = T[m * 5 + 2];
    tab[2 * m]     = T[m * 5 + 3];
    tab[2 * m + 1] = T[m * 5 + 4];
    if (v) atomicOr(&validw[m >> 5], 1u << (m & 31));
  }
  for (int i = tid; i < 512; i += BLK) {
    if (i < n_targs) {
      int pi = srt[i];
      spx[i] = P[pi * 5 + 1];
      spy[i] = P[pi * 5 + 2];
      spa[i] = P[pi * 5 + 3];
      spb[i] = P[pi * 5 + 4];
    } else {
      spx[i] = 0.f; spy[i] = 0.f; spa[i] = 0.f; spb[i] = 0.f;
    }
  }
  __syncthreads();

  // ---- Phase A: per-pred top-16 sorted candidate list ----
  uint32_t lep[8];
#pragma unroll
  for (int j = 0; j < 8; ++j) lep[j] = 0;
  const float4* t4 = (const float4*)txy;
  for (int r = tid; r < K; r += BLK) {
    float x = spx[r], y = spy[r];
    uint32_t cur[16];
#pragma unroll
    for (int j = 0; j < 16; ++j) cur[j] = 0xFFFFFFFFu;
    for (int c = 0; c < 32; ++c) {
      uint32_t nk[16];
#pragma unroll
      for (int jj = 0; jj < 8; ++jj) {
        float4 v = t4[c * 8 + jj];
        int t0 = c * 16 + jj * 2;
        float dx0 = __fsub_rn(v.x, x), dy0 = __fsub_rn(v.y, y);
        float d20 = __fadd_rn(__fmul_rn(dx0, dx0), __fmul_rn(dy0, dy0));
        nk[jj * 2] = (__float_as_uint(d20) & 0xFFFFFE00u) | (uint32_t)t0;
        float dx1 = __fsub_rn(v.z, x), dy1 = __fsub_rn(v.w, y);
        float d21 = __fadd_rn(__fmul_rn(dx1, dx1), __fmul_rn(dy1, dy1));
        nk[jj * 2 + 1] = (__float_as_uint(d21) & 0xFFFFFE00u) | (uint32_t)(t0 + 1);
      }
      bsort16(nk);
#pragma unroll
      for (int j = 0; j < 16; ++j) {
        uint32_t o = nk[15 - j];
        cur[j] = cur[j] < o ? cur[j] : o;
      }
      bclean16(cur);
    }
#pragma unroll
    for (int j = 0; j < 16; ++j) lists[r * 16 + j] = (uint16_t)(cur[j] & 0x1FFu);
    if (r == tid) {
#pragma unroll
      for (int j = 0; j < 8; ++j)
        lep[j] = (cur[2 * j] & 0x1FFu) | ((cur[2 * j + 1] & 0x1FFu) << 16);
    }
  }
  __syncthreads();

  // ---- Phase B: Jacobi fixpoint greedy ----
  for (int r = tid; r < K; r += BLK) picks[r] = lists[r * 16];   // init = entry 0
  __syncthreads();

  int iter = 0;
  while (true) {
    if (tid == 0) s_changed = 0;
    owner[tid] = 0xFFFFFFFFu;
    owner[tid + BLK] = 0xFFFFFFFFu;
    __syncthreads();
    // claims
    {
      int r = tid;
      if (r < K) { uint32_t p = picks[r]; if (p != 0xFFFFu) atomicMin(&owner[p], (uint32_t)r); }
      r = tid + BLK;
      if (r < K) { uint32_t p = picks[r]; if (p != 0xFFFFu) atomicMin(&owner[p], (uint32_t)r); }
    }
    __syncthreads();
    // rescan
    bool ch = false;
    {
      int r = tid;
      bool resv = (s_res[(r & 511) >> 5] >> (r & 31)) & 1;
      if (r < K && !resv) {
        uint32_t m = 0;
#pragma unroll
        for (int j = 0; j < 16; ++j) {
          uint32_t t = (j & 1) ? (lep[j >> 1] >> 16) : (lep[j >> 1] & 0xFFFFu);
          uint32_t o = owner[t];
          m |= (o >= (uint32_t)r) ? (1u << j) : 0u;
        }
        uint32_t np = 0xFFFFu;
        if (m) np = sel16le(lep, (uint32_t)(__ffs(m) - 1));
        if (np != picks[r]) { picks[r] = np; ch = true; }
      }
    }
    {
      int r = tid + BLK;
      if (r < K) {
        bool resv = (s_res[(r & 511) >> 5] >> (r & 31)) & 1;
        if (!resv) {
          uint32_t tt[16];
#pragma unroll
          for (int j = 0; j < 16; ++j) tt[j] = lists[r * 16 + j];
          uint32_t m = 0;
#pragma unroll
          for (int j = 0; j < 16; ++j) {
            uint32_t o = owner[tt[j]];
            m |= (o >= (uint32_t)r) ? (1u << j) : 0u;
          }
          uint32_t np = 0xFFFFu;
          if (m) {
            uint32_t js = (uint32_t)(__ffs(m) - 1);
            np = tt[0];
#pragma unroll
            for (int j = 1; j < 16; ++j) np = (js == (uint32_t)j) ? tt[j] : np;
          }
          if (np != picks[r]) { picks[r] = np; ch = true; }
        }
      }
    }
    if (ch) s_changed = 1;
    __syncthreads();

    if (s_changed == 0) {
      // converged: first pred with no pick (definitively exhausted)
      if (tid == 0) s_event = 0x7FFFFFFF;
      __syncthreads();
      {
        int r = tid;
        if (r < K && picks[r] == 0xFFFFu) atomicMin(&s_event, r);
        r = tid + BLK;
        if (r < K && picks[r] == 0xFFFFu) atomicMin(&s_event, r);
      }
      __syncthreads();
      int e = s_event;
      if (e >= K) break;   // all matched
      // rebuild availability from preds < e (they are final)
      if (tid < 16) avail[tid] = validw[tid];
      __syncthreads();
      {
        int r = tid;
        if (r < e) { uint32_t p = picks[r]; atomicAnd(&avail[p >> 5], ~(1u << (p & 31))); }
        r = tid + BLK;
        if (r < e) { uint32_t p = picks[r]; atomicAnd(&avail[p >> 5], ~(1u << (p & 31))); }
      }
      __syncthreads();
      // exact block argmin over avail for pred e
      {
        float x = spx[e], y = spy[e];
        const float INF = __builtin_inff();
        int t0 = tid, t1 = tid + BLK;
        float dx0 = __fsub_rn(txy[2 * t0], x), dy0 = __fsub_rn(txy[2 * t0 + 1], y);
        float d0 = __fadd_rn(__fmul_rn(dx0, dx0), __fmul_rn(dy0, dy0));
        if (!((avail[t0 >> 5] >> (t0 & 31)) & 1)) d0 = INF;
        float dx1 = __fsub_rn(txy[2 * t1], x), dy1 = __fsub_rn(txy[2 * t1 + 1], y);
        float d1 = __fadd_rn(__fmul_rn(dx1, dx1), __fmul_rn(dy1, dy1));
        if (!((avail[t1 >> 5] >> (t1 & 31)) & 1)) d1 = INF;
        float dl = (d1 < d0) ? d1 : d0;
        uint32_t tl = (d1 < d0) ? (uint32_t)t1 : (uint32_t)t0;
        float g = wave_min_f32_l63(dl);
        uint32_t cnd = (dl == g) ? tl : 0x7FFFFFFFu;
        uint32_t tw = wave_min_u32_l63(cnd);
        if ((tid & 63) == 0)
          wavemin[tid >> 6] = ((uint64_t)__float_as_uint(g) << 32) | tw;
      }
      __syncthreads();
      if (tid == 0) {
        uint64_t k0 = wavemin[0], k1 = wavemin[1];
        uint64_t k2 = wavemin[2], k3 = wavemin[3];
        uint64_t ka = k0 < k1 ? k0 : k1;
        uint64_t kb = k2 < k3 ? k2 : k3;
        uint64_t km = ka < kb ? ka : kb;
        int ts = (int)(km & 0xFFFFFFFFu);
        picks[e] = (uint16_t)ts;
        s_res[e >> 5] |= (1u << (e & 31));
      }
      __syncthreads();
      // resume fixpoint (forced pick may displace later preds)
    }
    if (++iter > 1100) break;   // safety cap (provably unreachable: ≤K+events rounds needed)
  }

  // ---- s_first: first valid target unused after all K matches ----
  if (tid < 16) avail[tid] = validw[tid];
  __syncthreads();
  {
    int r = tid;
    if (r < K) { uint32_t p = picks[r]; atomicAnd(&avail[p >> 5], ~(1u << (p & 31))); }
    r = tid + BLK;
    if (r < K) { uint32_t p = picks[r]; atomicAnd(&avail[p >> 5], ~(1u << (p & 31))); }
  }
  __syncthreads();
  if (tid == 0) {
    int f = 0;
    for (int w = 0; w < 16; ++w) {
      uint32_t a = avail[w];
      if (a) { f = w * 32 + __ffs(a) - 1; break; }
    }
    s_first = f;
  }
  __syncthreads();

  // ---- Phase C: fused MSE ----
  float ax = 0.f, ay = 0.f, aa = 0.f, ab = 0.f;
  for (int r = tid; r < K; r += BLK) {
    int m = picks[r];
    float dx = __fsub_rn(spx[r], txy[2 * m]);
    float dy = __fsub_rn(spy[r], txy[2 * m + 1]);
    float da = __fsub_rn(spa[r], tab[2 * m]);
    float db = __fsub_rn(spb[r], tab[2 * m + 1]);
    ax += __fmul_rn(dx, dx);
    ay += __fmul_rn(dy, dy);
    aa += __fmul_rn(da, da);
    ab += __fmul_rn(db, db);
  }
  if (n_pos < n_targs) {
    int f = s_first;
    float fx = txy[2 * f], fy = txy[2 * f + 1];
    float fa = tab[2 * f], fb = tab[2 * f + 1];
    for (int i = n_pos + tid; i < n_targs; i += BLK) {
      float dx = __fsub_rn(spx[i], fx);
      float dy = __fsub_rn(spy[i], fy);
      float da = __fsub_rn(spa[i], fa);
      float db = __fsub_rn(spb[i], fb);
      ax += __fmul_rn(dx, dx);
      ay += __fmul_rn(dy, dy);
      aa += __fmul_rn(da, da);
      ab += __fmul_rn(db, db);
    }
  }
  red[0][tid] = (double)ax;
  red[1][tid] = (double)ay;
  red[2][tid] = (double)aa;
  red[3][tid] = (double)ab;
  __syncthreads();
  for (int s = BLK / 2; s > 0; s >>= 1) {
    if (tid < s) {
#pragma unroll
      for (int c = 0; c < 4; ++c) red[c][tid] += red[c][tid + s];
    }
    __syncthreads();
  }
  if (tid == 0) {
#pragma unroll
    for (int c = 0; c < 4; ++c) atomicAdd(&acc[c], red[c][0]);
  }
}

__global__ void finalize_kernel(const double* __restrict__ acc,
                                float* __restrict__ out, double inv) {
  int c = threadIdx.x;
  if (c < 5) out[c] = (float)(acc[c] * inv);
}

extern "C" void kernel_launch(void* const* d_in, const int* in_sizes, int n_in,
                              void* d_out, int out_size, void* d_ws, size_t ws_size,
                              hipStream_t stream) {
  const float* preds = (const float*)d_in[0];
  const float* targets = (const float*)d_in[1];
  int B = in_sizes[0] / (NPRED * 5);

  double* acc = (double*)d_ws;
  uint8_t* recs = (uint8_t*)d_ws + 64;

  hipMemsetAsync(acc, 0, 5 * sizeof(double), stream);
  prep_kernel<<<B, BLK, 0, stream>>>(preds, targets, recs, acc);
  match_mse_kernel<<<B, BLK, 0, stream>>>(preds, targets, recs, acc);
  finalize_kernel<<<1, 64, 0, stream>>>(acc, (float*)d_out,
                                        1.0 / ((double)B * NPRED));
}

// Round 8
// 85.327 us; speedup vs baseline: 3.6100x; 3.6100x over previous
//
#include <hip/hip_runtime.h>
#include <stdint.h>

#define NPRED 2048
#define MT    512
#define BLK   256
#define NCAND 512

template<int C>
__device__ __forceinline__ uint32_t dppminu(uint32_t v) {
  uint32_t o = (uint32_t)__builtin_amdgcn_update_dpp((int)v, (int)v, C, 0xF, 0xF, false);
  return v < o ? v : o;
}
__device__ __forceinline__ uint32_t wave_min_u32_l63(uint32_t v) {
  v = dppminu<0x111>(v); v = dppminu<0x112>(v); v = dppminu<0x114>(v);
  v = dppminu<0x118>(v); v = dppminu<0x142>(v); v = dppminu<0x143>(v);
  return (uint32_t)__builtin_amdgcn_readlane((int)v, 63);
}
__device__ __forceinline__ uint32_t rowmin16(uint32_t v) {  // lane15/31/47/63 hold row min
  v = dppminu<0x111>(v); v = dppminu<0x112>(v);
  v = dppminu<0x114>(v); v = dppminu<0x118>(v);
  return v;
}

__global__ __launch_bounds__(BLK) void loss_kernel(const float* __restrict__ preds,
                                                   const float* __restrict__ targets,
                                                   double* __restrict__ acc) {
  const int b = blockIdx.x;
  const float* __restrict__ P = preds   + (size_t)b * NPRED * 5;
  const float* __restrict__ T = targets + (size_t)b * MT * 5;

  __shared__ uint64_t keys[NPRED];                     // 16 KB
  __shared__ uint64_t cand[NCAND];                     // 4 KB
  __shared__ float txy[MT * 2];                        // 4 KB (tx,ty interleaved)
  __shared__ float tab[MT * 2];                        // 4 KB (ta,tb interleaved)
  __shared__ float spx[520], spy[520], spa[520], spb[520]; // 8.3 KB
  __shared__ uint16_t plds[512];                       // 1 KB
  __shared__ int hist[256];                            // 1 KB
  __shared__ uint32_t validw[16];
  __shared__ int s_npos, s_nt, s_B, s_ncand, s_first;
  __shared__ uint64_t s_thr;
  __shared__ double red[5][BLK];                       // 10 KB

  const int tid = threadIdx.x;
  if (tid == 0) { s_npos = 0; s_nt = 0; s_B = 0; s_ncand = 0; s_first = 0; s_thr = 0ull; }
  hist[tid] = 0;
  if (tid < 16) validw[tid] = 0;
  // zero-pad sp arrays (pads [n_targs,520) must read as 0)
  for (int i = tid; i < 520; i += BLK) { spx[i] = 0.f; spy[i] = 0.f; spa[i] = 0.f; spb[i] = 0.f; }
  __syncthreads();

  // ---- keys + histogram of conf in [0.5,1) + n_pos ----
  int cpos = 0;
  for (int i = tid; i < NPRED; i += BLK) {
    float c = P[i * 5 + 0];
    cpos += (c > 0.5f) ? 1 : 0;
    uint32_t cb = __float_as_uint(c);
    keys[i] = ((uint64_t)(~cb) << 32) | (uint32_t)i;   // asc key == conf desc, idx asc
    if (cb >= 0x3F000000u && cb < 0x3F800000u)
      atomicAdd(&hist[(cb >> 15) & 0xFF], 1);
  }
  atomicAdd(&s_npos, cpos);

  // ---- stage targets + validity + n_targs ----
  int ct = 0;
  for (int m = tid; m < MT; m += BLK) {
    float tp = T[m * 5 + 0];
    bool v = (tp == 1.0f);
    if (v) { ct++; atomicOr(&validw[m >> 5], 1u << (m & 31)); }
    txy[2 * m]     = T[m * 5 + 1];
    txy[2 * m + 1] = T[m * 5 + 2];
    tab[2 * m]     = T[m * 5 + 3];
    tab[2 * m + 1] = T[m * 5 + 4];
  }
  atomicAdd(&s_nt, ct);
  __syncthreads();
  const int n_pos = s_npos;
  const int n_targs = s_nt;

  // ---- wave0: suffix-scan histogram -> cutoff bucket B ----
  if (tid < 64) {
    const int lane = tid;
    int4 h4 = *reinterpret_cast<const int4*>(&hist[lane * 4]);
    int t = h4.x + h4.y + h4.z + h4.w;
    int S = t;
#pragma unroll
    for (int off = 1; off < 64; off <<= 1) {
      int o = __shfl_down(S, off);
      if (lane + off < 64) S += o;
    }
    int Snext = S - t;
    int s3 = h4.w + Snext;
    int s2 = h4.z + s3;
    int s1 = h4.y + s2;
    int s0 = h4.x + s1;
    int localB = -1;
    if      (s3 >= n_targs) localB = lane * 4 + 3;
    else if (s2 >= n_targs) localB = lane * 4 + 2;
    else if (s1 >= n_targs) localB = lane * 4 + 1;
    else if (s0 >= n_targs) localB = lane * 4 + 0;
    uint64_t q = __ballot(localB >= 0);
    if (q) {
      int hl = 63 - __clzll((long long)q);
      int B = __builtin_amdgcn_readlane(localB, hl);
      if (lane == 0) s_B = B;
    }
  }
  __syncthreads();
  const int B = s_B;

  // ---- gather candidates (bucket >= B) ----
  for (int i = tid; i < NPRED; i += BLK) {
    uint64_t k = keys[i];
    uint32_t cb = ~(uint32_t)(k >> 32);
    if (cb >= 0x3F000000u && cb < 0x3F800000u && (int)((cb >> 15) & 0xFF) >= B) {
      int slot = atomicAdd(&s_ncand, 1);
      if (slot < NCAND) cand[slot] = k;
    }
  }
  __syncthreads();
  const int ncand = min(s_ncand, NCAND);

  // ---- rank-sort: scatter pred rows into sp* by rank; thrkey at rank n_targs-1 ----
  {
    uint64_t ka = (tid < ncand) ? cand[tid] : ~0ull;
    uint64_t kb = (tid + BLK < ncand) ? cand[tid + BLK] : ~0ull;
    int ra = 0, rb = 0;
    for (int j = 0; j < ncand; ++j) {
      uint64_t kj = cand[j];
      ra += (kj < ka) ? 1 : 0;
      rb += (kj < kb) ? 1 : 0;
    }
    if (tid < ncand && ra < n_targs) {
      int idx = (int)(ka & 0xFFFFFFFFu);
      spx[ra] = P[idx * 5 + 1]; spy[ra] = P[idx * 5 + 2];
      spa[ra] = P[idx * 5 + 3]; spb[ra] = P[idx * 5 + 4];
    }
    if (tid < ncand && ra == n_targs - 1) s_thr = ka;
    if (tid + BLK < ncand && rb < n_targs) {
      int idx = (int)(kb & 0xFFFFFFFFu);
      spx[rb] = P[idx * 5 + 1]; spy[rb] = P[idx * 5 + 2];
      spa[rb] = P[idx * 5 + 3]; spb[rb] = P[idx * 5 + 4];
    }
    if (tid + BLK < ncand && rb == n_targs - 1) s_thr = kb;
  }
  __syncthreads();
  const uint64_t thr = s_thr;
  const int K = min(n_pos, n_targs);

  float accp = 0.f;

  if (tid < 64) {
    // ---- wave0: 4-pred group-split greedy match ----
    const int lane = tid;
    const int s = lane & 15;     // target-word index (targets s*32 .. s*32+31)
    const int g = lane >> 4;     // group 0..3 -> pred i+g
    const uint32_t sbase = (uint32_t)(s << 5);

    float txr[32], tyr[32];
#pragma unroll
    for (int j = 0; j < 32; ++j) {
      txr[j] = txy[2 * (s * 32 + j)];
      tyr[j] = txy[2 * (s * 32 + j) + 1];
    }
    uint32_t una = ~validw[s];   // 1 = invalid-or-used

    int i = 0;
    float x = spx[g], y = spy[g];
    while (i + 4 <= K) {
      float xn = spx[i + 4 + g], yn = spy[i + 4 + g];   // prefetch next quad
      uint32_t kk = 0xFFFFFFFFu;
#pragma unroll
      for (int j = 0; j < 32; ++j) {
        float dx = __fsub_rn(txr[j], x);
        float dy = __fsub_rn(tyr[j], y);
        float d2 = __fadd_rn(__fmul_rn(dx, dx), __fmul_rn(dy, dy));
        uint32_t pois = 0u - ((una >> j) & 1u);
        uint32_t key = ((__float_as_uint(d2) & 0xFFFFFE00u) | (sbase + (uint32_t)j)) | pois;
        kk = kk < key ? kk : key;
      }
      kk = rowmin16(kk);
      uint32_t m0 = (uint32_t)__builtin_amdgcn_readlane((int)kk, 15) & 0x1FFu;
      uint32_t m1 = (uint32_t)__builtin_amdgcn_readlane((int)kk, 31) & 0x1FFu;
      uint32_t m2 = (uint32_t)__builtin_amdgcn_readlane((int)kk, 47) & 0x1FFu;
      uint32_t m3 = (uint32_t)__builtin_amdgcn_readlane((int)kk, 63) & 0x1FFu;
      int p;
      if (m1 == m0) p = 1;
      else if (m2 == m0 || m2 == m1) p = 2;
      else if (m3 == m0 || m3 == m1 || m3 == m2) p = 3;
      else p = 4;
      // commit distinct prefix (exact: removing non-minimizers preserves argmin)
      uint32_t hit = ((m0 >> 5) == (uint32_t)s) ? (1u << (m0 & 31u)) : 0u;
      if (p > 1) hit |= ((m1 >> 5) == (uint32_t)s) ? (1u << (m1 & 31u)) : 0u;
      if (p > 2) hit |= ((m2 >> 5) == (uint32_t)s) ? (1u << (m2 & 31u)) : 0u;
      if (p > 3) hit |= ((m3 >> 5) == (uint32_t)s) ? (1u << (m3 & 31u)) : 0u;
      una |= hit;
      if (lane == 0) {
        plds[i] = (uint16_t)m0;
        if (p > 1) plds[i + 1] = (uint16_t)m1;
        if (p > 2) plds[i + 2] = (uint16_t)m2;
        if (p > 3) plds[i + 3] = (uint16_t)m3;
      }
      i += p;
      if (p == 4) { x = xn; y = yn; }
      else       { x = spx[i + g]; y = spy[i + g]; }   // rare re-read
    }
    // tail: single-pred steps (all groups redundant; row0 result used)
    while (i < K) {
      float x1 = spx[i], y1 = spy[i];
      uint32_t kk = 0xFFFFFFFFu;
#pragma unroll
      for (int j = 0; j < 32; ++j) {
        float dx = __fsub_rn(txr[j], x1);
        float dy = __fsub_rn(tyr[j], y1);
        float d2 = __fadd_rn(__fmul_rn(dx, dx), __fmul_rn(dy, dy));
        uint32_t pois = 0u - ((una >> j) & 1u);
        uint32_t key = ((__float_as_uint(d2) & 0xFFFFFE00u) | (sbase + (uint32_t)j)) | pois;
        kk = kk < key ? kk : key;
      }
      kk = rowmin16(kk);
      uint32_t m = (uint32_t)__builtin_amdgcn_readlane((int)kk, 15) & 0x1FFu;
      una |= ((m >> 5) == (uint32_t)s) ? (1u << (m & 31u)) : 0u;
      if (lane == 0) plds[i] = (uint16_t)m;
      ++i;
    }
    // first valid unused target
    uint32_t av = ~una;
    uint32_t fi = av ? (sbase + (uint32_t)__ffs(av) - 1u) : 0xFFFFFFFFu;
    fi = wave_min_u32_l63(fi);
    if (lane == 0) s_first = (fi < MT) ? (int)fi : 0;
  } else {
    // ---- waves 1-3: prob loss (t = key <= thrkey) ----
    for (int i = tid - 64; i < NPRED; i += (BLK - 64)) {
      uint64_t k = keys[i];
      float p = __uint_as_float(~(uint32_t)(k >> 32));
      accp += (k <= thr) ? -fmaxf(logf(p), -100.0f)
                         : -fmaxf(log1pf(-p), -100.0f);
    }
  }
  __syncthreads();

  // ---- fused MSE over matched pairs + case_first ----
  float ax = 0.f, ay = 0.f, aa = 0.f, ab = 0.f;
  for (int r = tid; r < K; r += BLK) {
    int m = plds[r];
    float dx = __fsub_rn(spx[r], txy[2 * m]);
    float dy = __fsub_rn(spy[r], txy[2 * m + 1]);
    float da = __fsub_rn(spa[r], tab[2 * m]);
    float db = __fsub_rn(spb[r], tab[2 * m + 1]);
    ax += __fmul_rn(dx, dx);
    ay += __fmul_rn(dy, dy);
    aa += __fmul_rn(da, da);
    ab += __fmul_rn(db, db);
  }
  if (n_pos < n_targs) {
    int f = s_first;
    float fx = txy[2 * f], fy = txy[2 * f + 1];
    float fa = tab[2 * f], fb = tab[2 * f + 1];
    for (int i = n_pos + tid; i < n_targs; i += BLK) {
      float dx = __fsub_rn(spx[i], fx);
      float dy = __fsub_rn(spy[i], fy);
      float da = __fsub_rn(spa[i], fa);
      float db = __fsub_rn(spb[i], fb);
      ax += __fmul_rn(dx, dx);
      ay += __fmul_rn(dy, dy);
      aa += __fmul_rn(da, da);
      ab += __fmul_rn(db, db);
    }
  }

  // ---- block reduce (doubles) + global atomic ----
  red[0][tid] = (double)ax;
  red[1][tid] = (double)ay;
  red[2][tid] = (double)aa;
  red[3][tid] = (double)ab;
  red[4][tid] = (double)accp;
  __syncthreads();
  for (int st = BLK / 2; st > 0; st >>= 1) {
    if (tid < st) {
#pragma unroll
      for (int c = 0; c < 5; ++c) red[c][tid] += red[c][tid + st];
    }
    __syncthreads();
  }
  if (tid == 0) {
#pragma unroll
    for (int c = 0; c < 5; ++c) atomicAdd(&acc[c], red[c][0]);
  }
}

__global__ void finalize_kernel(const double* __restrict__ acc,
                                float* __restrict__ out, double inv) {
  int c = threadIdx.x;
  if (c < 5) out[c] = (float)(acc[c] * inv);
}

extern "C" void kernel_launch(void* const* d_in, const int* in_sizes, int n_in,
                              void* d_out, int out_size, void* d_ws, size_t ws_size,
                              hipStream_t stream) {
  const float* preds = (const float*)d_in[0];
  const float* targets = (const float*)d_in[1];
  int B = in_sizes[0] / (NPRED * 5);

  double* acc = (double*)d_ws;
  hipMemsetAsync(acc, 0, 5 * sizeof(double), stream);
  loss_kernel<<<B, BLK, 0, stream>>>(preds, targets, acc);
  finalize_kernel<<<1, 64, 0, stream>>>(acc, (float*)d_out,
                                        1.0 / ((double)B * NPRED));
}